// Round 3
// baseline (1962.143 us; speedup 1.0000x reference)
//
#include <hip/hip_runtime.h>
#include <stdint.h>

#define XY 32
#define ZS 16
#define NST 16384          // N = XY*XY*ZS
#define NMASK 16383
#define VOC 10000
#define BB 32
#define TT 64
#define LL 16

#define NCHUNK 8
#define CSZ 2048                 // states per chunk
#define STAGE_N (CSZ + CSZ + 32) // prev-score range [c0-2048, c0+2080) = 4128
#define STAGE_PAD 4160           // padded for 16B alignment of what follows

#define LOG2E 1.4426950408889634f
#define LN2F  0.6931471805599453f

__device__ __forceinline__ float fexp2(float x) {
#if __has_builtin(__builtin_amdgcn_exp2f)
  return __builtin_amdgcn_exp2f(x);
#else
  return exp2f(x);
#endif
}
__device__ __forceinline__ float flog2(float x) {   // log base 2
#if __has_builtin(__builtin_amdgcn_logf)
  return __builtin_amdgcn_logf(x);
#else
  return log2f(x);
#endif
}

__device__ __forceinline__ float waveMax(float v) {
  #pragma unroll
  for (int o = 32; o >= 1; o >>= 1) v = fmaxf(v, __shfl_xor(v, o, 64));
  return v;
}
__device__ __forceinline__ float waveSum(float v) {
  #pragma unroll
  for (int o = 32; o >= 1; o >>= 1) v += __shfl_xor(v, o, 64);
  return v;
}

// ---------------------------------------------------------------- small prep
__global__ __launch_bounds__(256) void tok_conv(const int* __restrict__ st,
                                                unsigned short* __restrict__ tok16) {
  int i = blockIdx.x * 256 + threadIdx.x;
  if (i >= BB * TT * LL) return;
  int l = i & 15;
  int tb = i >> 4;
  int b = tb & 31;
  int t = tb >> 5;
  tok16[i] = (unsigned short)st[b * (TT * LL) + t * LL + l];
}

// Transition softmax, j-major output: TnG[j*NST + n] = softmax(trans[n,:])[j].
__global__ __launch_bounds__(256) void prep_trans(const float* __restrict__ tr,
                                                  float* __restrict__ TnG) {
  int n = blockIdx.x * 256 + threadIdx.x;
  if (n >= NST) return;
  float v[7];
  float m = -3.4e38f;
  #pragma unroll
  for (int k = 0; k < 7; ++k) { v[k] = tr[n * 7 + k]; m = fmaxf(m, v[k]); }
  float s = 0.f;
  #pragma unroll
  for (int k = 0; k < 7; ++k) { v[k] = fexp2((v[k] - m) * LOG2E); s += v[k]; }
  float inv = 1.0f / s;
  #pragma unroll
  for (int k = 0; k < 7; ++k) TnG[k * NST + n] = v[k] * inv;
}

__global__ __launch_bounds__(256) void lse_prior(const float* __restrict__ prior,
                                                 float* __restrict__ lse_p) {
  int tid = threadIdx.x;
  __shared__ float sred[8];
  float lmax = -3.4e38f;
  for (int n = tid; n < NST; n += 256) lmax = fmaxf(lmax, prior[n]);
  float wm = waveMax(lmax);
  if ((tid & 63) == 0) sred[tid >> 6] = wm;
  __syncthreads();
  float bm = fmaxf(fmaxf(sred[0], sred[1]), fmaxf(sred[2], sred[3]));
  float ls = 0.f;
  for (int n = tid; n < NST; n += 256) ls += fexp2((prior[n] - bm) * LOG2E);
  float ws = waveSum(ls);
  if ((tid & 63) == 0) sred[4 + (tid >> 6)] = ws;
  __syncthreads();
  if (tid == 0)
    lse_p[0] = bm + flog2(sred[4] + sred[5] + sred[6] + sred[7]) * LN2F;
}

__global__ __launch_bounds__(64) void init_flags(int* flags) {
  flags[threadIdx.x + blockIdx.x * 64] = -1;   // insurance vs stale-flag replay
}

// ---------------------------------------------------------------- emissions
// One WG per state n: stage emis row in LDS, row LSE, gather token sums.
// em[n][i], i=t*32+b, PRE-SCALED by LOG2E (log2 domain).
__global__ __launch_bounds__(256) void emis_kernel(const float* __restrict__ emis,
                                                   const unsigned short* __restrict__ tok16,
                                                   float* __restrict__ em) {
  const int n = blockIdx.x;
  const int tid = threadIdx.x;
  __shared__ float row[VOC];
  __shared__ float sred[8];

  const float4* rp = (const float4*)(emis + (size_t)n * VOC);
  float4 regs[10];
  float lmax = -3.4e38f;
  #pragma unroll
  for (int it = 0; it < 10; ++it) {
    int i = tid + it * 256;
    if (i < VOC / 4) {
      float4 v = rp[i];
      regs[it] = v;
      ((float4*)row)[i] = v;
      lmax = fmaxf(lmax, fmaxf(fmaxf(v.x, v.y), fmaxf(v.z, v.w)));
    }
  }
  float wm = waveMax(lmax);
  if ((tid & 63) == 0) sred[tid >> 6] = wm;
  __syncthreads();
  float bm = fmaxf(fmaxf(sred[0], sred[1]), fmaxf(sred[2], sred[3]));

  float ls = 0.f;
  #pragma unroll
  for (int it = 0; it < 10; ++it) {
    int i = tid + it * 256;
    if (i < VOC / 4) {
      float4 v = regs[it];
      ls += fexp2((v.x - bm) * LOG2E);
      ls += fexp2((v.y - bm) * LOG2E);
      ls += fexp2((v.z - bm) * LOG2E);
      ls += fexp2((v.w - bm) * LOG2E);
    }
  }
  float wsum = waveSum(ls);
  if ((tid & 63) == 0) sred[4 + (tid >> 6)] = wsum;
  __syncthreads();
  float lse = bm + flog2(sred[4] + sred[5] + sred[6] + sred[7]) * LN2F;
  float sub = (float)LL * lse;

  for (int i = tid; i < TT * BB; i += 256) {
    const uint4* tp = (const uint4*)(tok16 + (size_t)i * 16);
    uint4 w0 = tp[0];
    uint4 w1 = tp[1];
    float s = row[w0.x & 0xFFFF] + row[w0.x >> 16]
            + row[w0.y & 0xFFFF] + row[w0.y >> 16]
            + row[w0.z & 0xFFFF] + row[w0.z >> 16]
            + row[w0.w & 0xFFFF] + row[w0.w >> 16]
            + row[w1.x & 0xFFFF] + row[w1.x >> 16]
            + row[w1.y & 0xFFFF] + row[w1.y >> 16]
            + row[w1.z & 0xFFFF] + row[w1.z >> 16]
            + row[w1.w & 0xFFFF] + row[w1.w >> 16];
    em[(size_t)n * (TT * BB) + i] = (s - sub) * LOG2E;
  }
}

// Transpose em[n][i] (16384 x 2048) -> em2[i][n] (2048 x 16384).
__global__ __launch_bounds__(256) void transpose_em(const float* __restrict__ em,
                                                    float* __restrict__ em2) {
  __shared__ float tile[64][65];
  const int i0 = blockIdx.x * 64;
  const int n0 = blockIdx.y * 64;
  const int tx = threadIdx.x & 63;
  const int ty = threadIdx.x >> 6;
  #pragma unroll
  for (int r = 0; r < 16; ++r) {
    int nr = ty + 4 * r;
    tile[nr][tx] = em[(size_t)(n0 + nr) * (TT * BB) + i0 + tx];
  }
  __syncthreads();
  #pragma unroll
  for (int r = 0; r < 16; ++r) {
    int ir = ty + 4 * r;
    em2[(size_t)(i0 + ir) * NST + n0 + tx] = tile[tx][ir];
  }
}

// ---------------------------------------------------------------- recursion
// 256 WGs = 32 batches x 8 chunks of 2048 states. Tn chunk cached in LDS once.
// Scores double-buffered in global; ring sync via agent-scope flags:
// chunk c @ step t needs chunks {c-1, c+1} (and itself) @ step t-1
// (offsets span [n-2048, n+32]). Release = syncthreads + agent release-store
// (wbL2); acquire = spin relaxed + agent acquire fence (L2 inv). Correct
// regardless of WG->XCD placement. 256 WGs, 74KB LDS -> >=1 WG/CU -> all
// co-resident -> no deadlock.
__global__ __launch_bounds__(256) void recursion_kernel(
    const float* __restrict__ em2,   // [TT*BB][NST] log2-domain emissions
    const float* __restrict__ TnG,   // [7][NST] transition probs
    const float* __restrict__ prior, // [NST] unnormalized ln
    const float* __restrict__ lse_p, // [1]
    float* __restrict__ S0,          // [BB][NST]
    float* __restrict__ S1,          // [BB][NST]
    int* flags,                      // [256], init -1
    float2* partials,                // [256]
    float* __restrict__ out) {
  extern __shared__ float lds[];
  float* stage = lds;                    // STAGE_PAD floats
  float* TnT   = lds + STAGE_PAD;        // [7][CSZ]
  float* red   = TnT + 7 * CSZ;          // 32 floats

  const int bid = blockIdx.x;
  const int b = bid & 31;
  const int c = bid >> 5;
  const int c0 = c * CSZ;
  const int tid = threadIdx.x;
  const int lbid = (((c + NCHUNK - 1) & (NCHUNK - 1)) << 5) | b;
  const int rbid = (((c + 1) & (NCHUNK - 1)) << 5) | b;

  // Cache this chunk's transition probs in LDS (transposed, conflict-free).
  #pragma unroll
  for (int j = 0; j < 7; ++j) {
    const float4* src = (const float4*)(TnG + (size_t)j * NST + c0);
    float4* dst = (float4*)(TnT + j * CSZ);
    for (int i = tid; i < CSZ / 4; i += 256) dst[i] = src[i];
  }

  // t = 0 init: own slice only.
  #pragma unroll
  for (int k = 0; k < 8; ++k) {
    int s = tid + (k << 8);
    int n = c0 + s;
    S0[(size_t)b * NST + n] = em2[(size_t)b * NST + n] + prior[n] * LOG2E;
  }
  __syncthreads();
  if (tid == 0)
    __hip_atomic_store(&flags[bid], 0, __ATOMIC_RELEASE, __HIP_MEMORY_SCOPE_AGENT);

  float vcur[8];
  for (int t = 1; t < TT; ++t) {
    const float* __restrict__ Sprev = (t & 1) ? S0 : S1;
    float* __restrict__ Scur = (t & 1) ? S1 : S0;

    if (tid == 0) {
      while (__hip_atomic_load(&flags[lbid], __ATOMIC_RELAXED,
                               __HIP_MEMORY_SCOPE_AGENT) < t - 1)
        __builtin_amdgcn_s_sleep(1);
      while (__hip_atomic_load(&flags[rbid], __ATOMIC_RELAXED,
                               __HIP_MEMORY_SCOPE_AGENT) < t - 1)
        __builtin_amdgcn_s_sleep(1);
    }
    __syncthreads();
    __builtin_amdgcn_fence(__ATOMIC_ACQUIRE, "agent");

    // Stage prev scores [c0-2048, c0+2080) mod NST into LDS.
    {
      const int base = (c0 - CSZ) & NMASK;
      const float* sp = Sprev + (size_t)b * NST;
      for (int i = tid; i < STAGE_N / 4; i += 256) {
        int idx = (base + 4 * i) & NMASK;   // float4 never straddles the wrap
        *(float4*)(stage + 4 * i) = *(const float4*)(sp + idx);
      }
    }
    __syncthreads();

    const float* __restrict__ e = em2 + (size_t)(t * BB + b) * NST + c0;
    #pragma unroll
    for (int k = 0; k < 8; ++k) {
      int s = tid + (k << 8);
      float p0 = stage[CSZ + s];            // n
      float a1 = stage[CSZ + s - 1];        // n-1
      float a2 = stage[CSZ + s + 1];        // n+1
      float a3 = stage[CSZ + s - 32];       // n-32
      float a4 = stage[CSZ + s + 32];       // n+32
      float p5 = stage[CSZ + s - 1024];     // n-1024
      float p6 = stage[s];                  // n-2048
      float t0 = TnT[0 * CSZ + s], t1 = TnT[1 * CSZ + s], t2 = TnT[2 * CSZ + s],
            t3 = TnT[3 * CSZ + s], t4 = TnT[4 * CSZ + s], t5 = TnT[5 * CSZ + s],
            t6 = TnT[6 * CSZ + s];
      float m = fmaxf(fmaxf(fmaxf(p0, a1), fmaxf(a2, a3)),
                      fmaxf(fmaxf(a4, p5), p6));
      float ssum = t0 * fexp2(p0 - m) + t1 * fexp2(a1 - m)
                 + t2 * fexp2(a2 - m) + t3 * fexp2(a3 - m)
                 + t4 * fexp2(a4 - m) + t5 * fexp2(p5 - m)
                 + t6 * fexp2(p6 - m);
      vcur[k] = e[s] + m + flog2(ssum);
    }

    if (t < TT - 1) {
      #pragma unroll
      for (int k = 0; k < 8; ++k)
        Scur[(size_t)b * NST + c0 + tid + (k << 8)] = vcur[k];
      __syncthreads();   // drains stores + protects stage reuse
      if (tid == 0)
        __hip_atomic_store(&flags[bid], t, __ATOMIC_RELEASE,
                           __HIP_MEMORY_SCOPE_AGENT);
    }
  }

  // Per-chunk partial LSE from registers (t = 63 values).
  float mr = vcur[0];
  #pragma unroll
  for (int k = 1; k < 8; ++k) mr = fmaxf(mr, vcur[k]);
  mr = waveMax(mr);
  if ((tid & 63) == 0) red[tid >> 6] = mr;
  __syncthreads();
  float M = fmaxf(fmaxf(red[0], red[1]), fmaxf(red[2], red[3]));
  float sr = 0.f;
  #pragma unroll
  for (int k = 0; k < 8; ++k) sr += fexp2(vcur[k] - M);
  sr = waveSum(sr);
  if ((tid & 63) == 0) red[4 + (tid >> 6)] = sr;
  __syncthreads();
  if (tid == 0) {
    partials[bid] = make_float2(M, red[4] + red[5] + red[6] + red[7]);
    __hip_atomic_store(&flags[bid], TT - 1, __ATOMIC_RELEASE,
                       __HIP_MEMORY_SCOPE_AGENT);
  }

  // Chunk 0 combines the 8 partials of its batch.
  if (c == 0 && tid == 0) {
    #pragma unroll
    for (int cc = 1; cc < NCHUNK; ++cc) {
      int fb = (cc << 5) | b;
      while (__hip_atomic_load(&flags[fb], __ATOMIC_RELAXED,
                               __HIP_MEMORY_SCOPE_AGENT) < TT - 1)
        __builtin_amdgcn_s_sleep(1);
    }
    __builtin_amdgcn_fence(__ATOMIC_ACQUIRE, "agent");
    float Mg = -3.4e38f, Sg = 0.f;
    #pragma unroll
    for (int cc = 0; cc < NCHUNK; ++cc) {
      float2 p = partials[(cc << 5) | b];
      float nm = fmaxf(Mg, p.x);
      Sg = Sg * fexp2(Mg - nm) + p.y * fexp2(p.x - nm);
      Mg = nm;
    }
    out[b] = LN2F * (Mg + flog2(Sg)) - lse_p[0];
  }
}

extern "C" void kernel_launch(void* const* d_in, const int* in_sizes, int n_in,
                              void* d_out, int out_size, void* d_ws, size_t ws_size,
                              hipStream_t stream) {
  const int* stories  = (const int*)d_in[0];
  const float* trans  = (const float*)d_in[3];
  const float* emis   = (const float*)d_in[4];
  const float* prior  = (const float*)d_in[5];
  float* out = (float*)d_out;

  char* ws = (char*)d_ws;
  float* em  = (float*)ws;                                  // 134.2 MB
  float* em2 = em + (size_t)NST * TT * BB;                  // 134.2 MB
  float* S0  = em2 + (size_t)NST * TT * BB;                 // 2 MB
  float* S1  = S0 + (size_t)BB * NST;                       // 2 MB
  float* TnG = S1 + (size_t)BB * NST;                       // 448 KB
  float2* partials = (float2*)(TnG + (size_t)7 * NST);      // 2 KB
  int* flags = (int*)(partials + 256);                      // 1 KB
  unsigned short* tok16 = (unsigned short*)(flags + 256);   // 64 KB
  float* lse_p = (float*)(tok16 + (size_t)BB * TT * LL);    // 4 B

  init_flags<<<4, 64, 0, stream>>>(flags);
  tok_conv<<<(BB * TT * LL + 255) / 256, 256, 0, stream>>>(stories, tok16);
  prep_trans<<<NST / 256, 256, 0, stream>>>(trans, TnG);
  lse_prior<<<1, 256, 0, stream>>>(prior, lse_p);
  emis_kernel<<<NST, 256, 0, stream>>>(emis, tok16, em);
  transpose_em<<<dim3(TT * BB / 64, NST / 64), 256, 0, stream>>>(em, em2);

  size_t dynlds = (size_t)(STAGE_PAD + 7 * CSZ + 32) * sizeof(float); // 74112 B
  hipFuncSetAttribute((const void*)recursion_kernel,
                      hipFuncAttributeMaxDynamicSharedMemorySize, (int)dynlds);
  recursion_kernel<<<BB * NCHUNK, 256, dynlds, stream>>>(
      em2, TnG, prior, lse_p, S0, S1, flags, partials, out);
}